// Round 10
// baseline (253.748 us; speedup 1.0000x reference)
//
#include <hip/hip_runtime.h>

#define N_NODES 10000
#define N_EDGES 160000
#define IN_DIM 128
#define HID 16
#define HEADS 50
#define OUT_DIM 10
#define N_GRAPHS 8
#define NHID (HEADS * HID) /* 800 */

// 8 head-groups: grp g owns heads [hstart(g), hstart(g+1)), 6 or 7 heads.
static __device__ __forceinline__ int hstart_of(int g) { return (g * 25) >> 2; }

typedef __attribute__((ext_vector_type(8))) short bfrag;   // 8 bf16 (4 VGPRs)
typedef __attribute__((ext_vector_type(4))) float ffrag;   // 4 fp32 acc

#define LOG2E 1.44269504088896340736f

// ---- bf16 helpers (self-contained, RNE) ----
static __device__ __forceinline__ unsigned short f2bf(float f) {
    union { float f; unsigned u; } v; v.f = f;
    unsigned u = v.u;
    unsigned r = (u + 0x7fffu + ((u >> 16) & 1u)) >> 16;
    return (unsigned short)r;
}
static __device__ __forceinline__ float bits2f(unsigned u) {
    union { unsigned u; float f; } v; v.u = u;
    return v.f;
}

// ---- K0: fused parallel prep: xcast | wcast(transpose) | hsum zero | edge count ----
__global__ __launch_bounds__(256) void prep_kernel(const float* __restrict__ x,
                                                   const float* __restrict__ W,
                                                   const int* __restrict__ ei,
                                                   unsigned short* __restrict__ xbf,
                                                   unsigned short* __restrict__ wt,
                                                   float* __restrict__ hsum,
                                                   int* __restrict__ cnt) {
    const int bid = blockIdx.x, tid = threadIdx.x;
    if (bid < 1250) {
        int t = bid * 256 + tid;  // exactly 320000
        float4 v = ((const float4*)x)[t];
        ushort4 o;
        o.x = f2bf(v.x); o.y = f2bf(v.y); o.z = f2bf(v.z); o.w = f2bf(v.w);
        ((ushort4*)xbf)[t] = o;
    } else if (bid < 1650) {
        int t = (bid - 1250) * 256 + tid;  // exactly 102400
        int n = t >> 7, k = t & 127;
        wt[t] = f2bf(W[k * NHID + n]);
    } else if (bid < 1807) {
        int t = (bid - 1650) * 256 + tid;
        if (t < 40000) ((float4*)hsum)[t] = make_float4(0.f, 0.f, 0.f, 0.f);
    } else {
        int e = (bid - 1807) * 256 + tid;
        if (e < N_EDGES) atomicAdd(&cnt[ei[N_EDGES + e]], 1);
    }
}

// ---- K1: MFMA bf16 GEMM, LDS-free, alpha fused (pre-scaled by log2e) ----
__global__ __launch_bounds__(256) void gemm_mfma(const unsigned short* __restrict__ xbf,
                                                 const unsigned short* __restrict__ wt,
                                                 const float* __restrict__ a_src,
                                                 const float* __restrict__ a_dst,
                                                 unsigned short* __restrict__ xpg,
                                                 float* __restrict__ astp,
                                                 float* __restrict__ adtp) {
    const int tid = threadIdx.x;
    const int wave = tid >> 6, lane = tid & 63;
    const int q = lane >> 4, r = lane & 15;
    const int m0 = blockIdx.y * 128 + wave * 32;
    const int h0 = blockIdx.x * 5;
    ffrag zf = {0.f, 0.f, 0.f, 0.f};
    ffrag acc[2][5];
#pragma unroll
    for (int mt = 0; mt < 2; mt++)
#pragma unroll
        for (int nt = 0; nt < 5; nt++) acc[mt][nt] = zf;

#pragma unroll
    for (int kc = 0; kc < IN_DIM; kc += 32) {
        bfrag a[2], b[5];
#pragma unroll
        for (int mt = 0; mt < 2; mt++)
            a[mt] = *(const bfrag*)(xbf + (m0 + mt * 16 + r) * IN_DIM + kc + q * 8);
#pragma unroll
        for (int nt = 0; nt < 5; nt++)
            b[nt] = *(const bfrag*)(wt + ((h0 + nt) * 16 + r) * IN_DIM + kc + q * 8);
#pragma unroll
        for (int mt = 0; mt < 2; mt++)
#pragma unroll
            for (int nt = 0; nt < 5; nt++)
                acc[mt][nt] = __builtin_amdgcn_mfma_f32_16x16x32_bf16(a[mt], b[nt],
                                                                      acc[mt][nt], 0, 0, 0);
    }
#pragma unroll
    for (int nt = 0; nt < 5; nt++) {
        const int h = h0 + nt;
        const int g = (8 * h + 7) / 50;
        const int hl = h - hstart_of(g);
        const float asw = a_src[h * HID + r] * LOG2E;
        const float adw = a_dst[h * HID + r] * LOG2E;
        unsigned short* xg = xpg + (size_t)g * (N_NODES * 128);
        float* ag = astp + g * (N_NODES * 8);
        float* dg = adtp + g * (N_NODES * 8);
#pragma unroll
        for (int mt = 0; mt < 2; mt++) {
            ffrag d = acc[mt][nt];  // rows m = m0+mt*16+q*4+i, col r
            float s[4], w[4];
#pragma unroll
            for (int i = 0; i < 4; i++) { s[i] = d[i] * asw; w[i] = d[i] * adw; }
#pragma unroll
            for (int off = 1; off < 16; off <<= 1) {
#pragma unroll
                for (int i = 0; i < 4; i++) {
                    s[i] += __shfl_xor(s[i], off);
                    w[i] += __shfl_xor(w[i], off);
                }
            }
#pragma unroll
            for (int i = 0; i < 4; i++) {
                const int node = m0 + mt * 16 + q * 4 + i;
                if (node < N_NODES) {
                    xg[node * 128 + hl * 16 + r] = f2bf(d[i]);
                    if (r == 0) {
                        ag[(node << 3) + hl] = s[i];
                        dg[(node << 3) + hl] = w[i];
                    }
                }
            }
        }
    }
}

// ---- K2: scan (1 block, shfl-based: 3 barriers): cnt -> offs/curs, hist -> dcur ----
__global__ __launch_bounds__(1024) void scan_kernel(const int* __restrict__ cnt,
                                                    int* __restrict__ offs,
                                                    int* __restrict__ curs,
                                                    int* __restrict__ dcur) {
    __shared__ int wsum[16];
    __shared__ int dh[64];
    const int t = threadIdx.x;
    const int wid = t >> 6, lane = t & 63;
    if (t < 64) dh[t] = 0;
    __syncthreads();
    const int base = t * 10;
    int local[10];
    int s = 0;
#pragma unroll
    for (int i = 0; i < 10; i++) {
        int idx = base + i;
        int v = (idx < N_NODES) ? cnt[idx] : 0;
        if (idx < N_NODES) { int bb = v < 63 ? v : 63; atomicAdd(&dh[63 - bb], 1); }
        local[i] = s;
        s += v;
    }
    int incl = s;  // wave-level inclusive scan via shfl_up
#pragma unroll
    for (int off = 1; off < 64; off <<= 1) {
        int u = __shfl_up(incl, off);
        if (lane >= off) incl += u;
    }
    if (lane == 63) wsum[wid] = incl;
    __syncthreads();
    if (wid == 0 && lane < 16) {
        int v = wsum[lane];
        int i2 = v;
#pragma unroll
        for (int off = 1; off < 16; off <<= 1) {
            int u = __shfl_up(i2, off);
            if (lane >= off) i2 += u;
        }
        wsum[lane] = i2 - v;  // exclusive wave offset
    }
    __syncthreads();
    const int texcl = (incl - s) + wsum[wid];
#pragma unroll
    for (int i = 0; i < 10; i++) {
        int idx = base + i;
        if (idx < N_NODES) {
            int o = texcl + local[i];
            offs[idx] = o;
            curs[idx] = o;
        }
    }
    if (t == 1023) offs[N_NODES] = texcl + s;  // == N_EDGES
    if (wid == 0) {
        int v = dh[lane];
        int i3 = v;
#pragma unroll
        for (int off = 1; off < 64; off <<= 1) {
            int u = __shfl_up(i3, off);
            if (lane >= off) i3 += u;
        }
        dcur[lane] = i3 - v;  // exclusive (descending-degree bins)
    }
}

// ---- K3: fused parallel scatter: edge scatter (src+dst) | degree-sort scatter ----
__global__ __launch_bounds__(256) void scatter_kernel(const int* __restrict__ ei,
                                                      int* __restrict__ curs,
                                                      int* __restrict__ ssrc,
                                                      int* __restrict__ edst,
                                                      const int* __restrict__ cnt,
                                                      int* __restrict__ dcur,
                                                      int* __restrict__ perm) {
    const int bid = blockIdx.x;
    if (bid < 625) {
        int e = bid * 256 + threadIdx.x;
        if (e < N_EDGES) {
            int d = ei[N_EDGES + e];
            int pos = atomicAdd(&curs[d], 1);
            ssrc[pos] = ei[e];
            edst[pos] = d;
        }
    } else {
        int n = (bid - 625) * 256 + threadIdx.x;
        if (n < N_NODES) {
            int d = cnt[n];
            d = d < 63 ? d : 63;
            int pos = atomicAdd(&dcur[63 - d], 1);  // descending degree
            perm[pos] = n;
        }
    }
}

// ---- K3b: edge weights, one lane per (edge, head-slot), fully coalesced ----
// grid 40000 = 8 grps x 5000; wave handles 8 edges x 8 head slots.
// wg[g][e][8] bf16, non-temporal (streamed; keep L2 for xpg).
__global__ __launch_bounds__(256) void ew_kernel(const float* __restrict__ astp,
                                                 const float* __restrict__ adtp,
                                                 const int* __restrict__ ssrc,
                                                 const int* __restrict__ edst,
                                                 unsigned short* __restrict__ wg) {
    const int t = threadIdx.x;
    const int wave = t >> 6, lane = t & 63;
    const int g = blockIdx.x & 7;
    const int eb = blockIdx.x >> 3;  // 0..4999
    const int e = (eb * 4 + wave) * 8 + (lane >> 3);
    const int hl = lane & 7;
    const int src = ssrc[e], dst = edst[e];
    const float a = astp[g * (N_NODES * 8) + (src << 3) + hl];
    const float d = adtp[g * (N_NODES * 8) + (dst << 3) + hl];
    float l = a + d;                 // already pre-scaled by log2e
    l = fmaxf(l, 0.2f * l);          // leaky relu (commutes with positive scale)
    const float w = exp2f(l);
    __builtin_nontemporal_store(f2bf(w), wg + (size_t)g * (N_EDGES * 8) + (e << 3) + hl);
}

// ---- K4: lean aggregation: no exp in the edge loop (weights precomputed) ----
// grid 20000 = 8 grps x 2500; wave owns dst = perm[db*4+wave].
__global__ __launch_bounds__(256) void agg_kernel(const unsigned short* __restrict__ xpg,
                                                  const float* __restrict__ astp,
                                                  const float* __restrict__ adtp,
                                                  const int* __restrict__ offs,
                                                  const int* __restrict__ ssrc,
                                                  const int* __restrict__ perm,
                                                  const unsigned short* __restrict__ wg,
                                                  float* __restrict__ hsum) {
    const int t = threadIdx.x;
    const int wave = t >> 6, lane = t & 63;
    const int g = blockIdx.x & 7;
    const int db = blockIdx.x >> 3;  // 0..2499
    const int cg = hstart_of(g + 1) - hstart_of(g);  // 6 or 7
    const int hl = lane >> 3;
    const int co = (hl << 4) + (lane & 7) * 2;  // element offset in 128-wide row
    const int dst = __builtin_amdgcn_readfirstlane(perm[db * 4 + wave]);
    const int start = __builtin_amdgcn_readfirstlane(offs[dst]);
    const int eend = __builtin_amdgcn_readfirstlane(offs[dst + 1]);
    const float* ag = astp + g * (N_NODES * 8);
    const unsigned short* xg = xpg + (size_t)g * (N_NODES * 128);
    const unsigned short* wgp = wg + (size_t)g * (N_EDGES * 8);
    const float adv = adtp[g * (N_NODES * 8) + (dst << 3) + hl];
    // self loop (computed once here; not in wg)
    float lS = ag[(dst << 3) + hl] + adv;
    lS = fmaxf(lS, 0.2f * lS);
    const float wS = exp2f(lS);
    const unsigned pS = *(const unsigned*)(xg + (dst << 7) + co);
    float den = wS;
    float acc0 = wS * bits2f(pS << 16);
    float acc1 = wS * bits2f(pS & 0xffff0000u);
    int e = start;
    for (; e + 1 < eend; e += 2) {
        const int s0 = __builtin_amdgcn_readfirstlane(ssrc[e]);
        const int s1 = __builtin_amdgcn_readfirstlane(ssrc[e + 1]);
        const unsigned short wb0 = __builtin_nontemporal_load(wgp + (e << 3) + hl);
        const unsigned short wb1 = __builtin_nontemporal_load(wgp + ((e + 1) << 3) + hl);
        const unsigned p0 = *(const unsigned*)(xg + (s0 << 7) + co);
        const unsigned p1 = *(const unsigned*)(xg + (s1 << 7) + co);
        const float w0 = bits2f(((unsigned)wb0) << 16);
        const float w1 = bits2f(((unsigned)wb1) << 16);
        den += w0 + w1;
        acc0 = fmaf(w0, bits2f(p0 << 16), acc0);
        acc0 = fmaf(w1, bits2f(p1 << 16), acc0);
        acc1 = fmaf(w0, bits2f(p0 & 0xffff0000u), acc1);
        acc1 = fmaf(w1, bits2f(p1 & 0xffff0000u), acc1);
    }
    for (; e < eend; e++) {
        const int s0 = __builtin_amdgcn_readfirstlane(ssrc[e]);
        const unsigned short wb0 = __builtin_nontemporal_load(wgp + (e << 3) + hl);
        const unsigned p0 = *(const unsigned*)(xg + (s0 << 7) + co);
        const float w0 = bits2f(((unsigned)wb0) << 16);
        den += w0;
        acc0 = fmaf(w0, bits2f(p0 << 16), acc0);
        acc1 = fmaf(w0, bits2f(p0 & 0xffff0000u), acc1);
    }
    const float inv = (hl < cg) ? (1.f / den) : 0.f;  // den>0: self loop
    float v0 = acc0 * inv, v1 = acc1 * inv;
    v0 += __shfl_xor(v0, 8);  v1 += __shfl_xor(v1, 8);
    v0 += __shfl_xor(v0, 16); v1 += __shfl_xor(v1, 16);
    v0 += __shfl_xor(v0, 32); v1 += __shfl_xor(v1, 32);
    if (lane < 8) {
        atomicAdd(&hsum[(dst << 4) + 2 * lane + 0], v0);
        atomicAdd(&hsum[(dst << 4) + 2 * lane + 1], v1);
    }
}

// ---- K5: per-graph mean pool (+ head mean + bias) + FC. One block per graph. ----
__global__ __launch_bounds__(256) void pool_kernel(const float* __restrict__ hsum,
                                                   const int* __restrict__ batch,
                                                   const float* __restrict__ bias,
                                                   const float* __restrict__ fc_w,
                                                   const float* __restrict__ fc_b,
                                                   float* __restrict__ out) {
    const int g = blockIdx.x;
    const int t = threadIdx.x;
    int a = 0, b = N_NODES;
    while (a < b) { int m = (a + b) >> 1; if (batch[m] < g) a = m + 1; else b = m; }
    const int lo = a;
    b = N_NODES;
    while (a < b) { int m = (a + b) >> 1; if (batch[m] < g + 1) a = m + 1; else b = m; }
    const int hi = a;
    const int cntn = hi - lo;
    float acc[16];
#pragma unroll
    for (int c = 0; c < 16; c++) acc[c] = 0.f;
    for (int n = lo + t; n < hi; n += 256) {
        const float4* r = (const float4*)(hsum + (n << 4));
        float4 v0 = r[0], v1 = r[1], v2 = r[2], v3 = r[3];
        acc[0] += v0.x; acc[1] += v0.y; acc[2] += v0.z; acc[3] += v0.w;
        acc[4] += v1.x; acc[5] += v1.y; acc[6] += v1.z; acc[7] += v1.w;
        acc[8] += v2.x; acc[9] += v2.y; acc[10] += v2.z; acc[11] += v2.w;
        acc[12] += v3.x; acc[13] += v3.y; acc[14] += v3.z; acc[15] += v3.w;
    }
    __shared__ float red[256][17];
#pragma unroll
    for (int c = 0; c < 16; c++) red[t][c] = acc[c];
    __syncthreads();
    for (int s = 128; s > 0; s >>= 1) {
        if (t < s)
#pragma unroll
            for (int c = 0; c < 16; c++) red[t][c] += red[t + s][c];
        __syncthreads();
    }
    __shared__ float pooled[16];
    if (t < 16) {
        float v = 0.f;
        if (cntn > 0) v = red[0][t] / ((float)cntn * (float)HEADS) + bias[t];
        pooled[t] = v;
    }
    __syncthreads();
    if (t < OUT_DIM) {
        float s = fc_b[t];
#pragma unroll
        for (int c = 0; c < HID; c++) s += pooled[c] * fc_w[c * OUT_DIM + t];
        out[g * OUT_DIM + t] = s;
    }
}

// ---- workspace layout (bytes) ----
#define XPG_OFF 0              /* 8*10000*8*16*2 = 20,480,000 */
#define ASTP_OFF 20480000      /* 8*10000*8*4    =  2,560,000 */
#define ADTP_OFF 23040000      /* 8*10000*8*4    =  2,560,000 */
#define XBF_OFF 25600000       /* 10000*128*2    =  2,560,000 (wt follows: OOB-read safe) */
#define WT_OFF 28160000        /* 800*128*2      =    204,800 */
#define SSRC_OFF 28364800      /* 160000*4       =    640,000 */
#define EDST_OFF 29004800      /* 160000*4       =    640,000 */
#define OFFS_OFF 29644800      /* 10001*4        =     40,064 padded */
#define CURS_OFF 29684864      /* 10000*4        =     40,000 */
#define PERM_OFF 29724864      /* 10000*4        =     40,000 */
#define HSUM_OFF 29764864      /* 10000*16*4     =    640,000 (zeroed in prep) */
#define CNT_OFF 30404864       /* 10000*4        =     40,000 (zeroed by memset) */
#define DCUR_OFF 30444864      /* 64*4           =        256 */
#define WG_OFF 30445120        /* 8*160000*8*2   = 20,480,000 */

extern "C" void kernel_launch(void* const* d_in, const int* in_sizes, int n_in,
                              void* d_out, int out_size, void* d_ws, size_t ws_size,
                              hipStream_t stream) {
    const float* x = (const float*)d_in[0];
    const int* ei = (const int*)d_in[1];
    const int* batch = (const int*)d_in[2];
    const float* W = (const float*)d_in[4];
    const float* a_src = (const float*)d_in[5];
    const float* a_dst = (const float*)d_in[6];
    const float* bias = (const float*)d_in[7];
    const float* fc_w = (const float*)d_in[8];
    const float* fc_b = (const float*)d_in[9];
    float* out = (float*)d_out;

    char* ws = (char*)d_ws;
    unsigned short* xpg = (unsigned short*)(ws + XPG_OFF);
    float* astp = (float*)(ws + ASTP_OFF);
    float* adtp = (float*)(ws + ADTP_OFF);
    unsigned short* xbf = (unsigned short*)(ws + XBF_OFF);
    unsigned short* wt = (unsigned short*)(ws + WT_OFF);
    int* ssrc = (int*)(ws + SSRC_OFF);
    int* edst = (int*)(ws + EDST_OFF);
    int* offs = (int*)(ws + OFFS_OFF);
    int* curs = (int*)(ws + CURS_OFF);
    int* perm = (int*)(ws + PERM_OFF);
    float* hsum = (float*)(ws + HSUM_OFF);
    int* cntc = (int*)(ws + CNT_OFF);
    int* dcur = (int*)(ws + DCUR_OFF);
    unsigned short* wg = (unsigned short*)(ws + WG_OFF);

    hipMemsetAsync(ws + CNT_OFF, 0, 40000, stream);
    prep_kernel<<<2432, 256, 0, stream>>>(x, W, ei, xbf, wt, hsum, cntc);
    gemm_mfma<<<dim3(10, (N_NODES + 127) / 128), 256, 0, stream>>>(
        xbf, wt, a_src, a_dst, xpg, astp, adtp);
    scan_kernel<<<1, 1024, 0, stream>>>(cntc, offs, curs, dcur);
    scatter_kernel<<<665, 256, 0, stream>>>(ei, curs, ssrc, edst, cntc, dcur, perm);
    ew_kernel<<<8 * (N_EDGES / 32), 256, 0, stream>>>(astp, adtp, ssrc, edst, wg);
    agg_kernel<<<8 * (N_NODES / 4), 256, 0, stream>>>(xpg, astp, adtp, offs, ssrc, perm, wg,
                                                      hsum);
    pool_kernel<<<N_GRAPHS, 256, 0, stream>>>(hsum, batch, bias, fc_w, fc_b, out);
}

// Round 11
// 212.054 us; speedup vs baseline: 1.1966x; 1.1966x over previous
//
#include <hip/hip_runtime.h>

#define N_NODES 10000
#define N_EDGES 160000
#define IN_DIM 128
#define HID 16
#define HEADS 50
#define OUT_DIM 10
#define N_GRAPHS 8
#define NHID (HEADS * HID) /* 800 */

// 8 head-groups: grp g owns heads [hstart(g), hstart(g+1)), 6 or 7 heads.
static __device__ __forceinline__ int hstart_of(int g) { return (g * 25) >> 2; }

typedef __attribute__((ext_vector_type(8))) short bfrag;   // 8 bf16 (4 VGPRs)
typedef __attribute__((ext_vector_type(4))) float ffrag;   // 4 fp32 acc

#define LOG2E 1.44269504088896340736f

// ---- bf16 helpers (self-contained, RNE) ----
static __device__ __forceinline__ unsigned short f2bf(float f) {
    union { float f; unsigned u; } v; v.f = f;
    unsigned u = v.u;
    unsigned r = (u + 0x7fffu + ((u >> 16) & 1u)) >> 16;
    return (unsigned short)r;
}
static __device__ __forceinline__ float bits2f(unsigned u) {
    union { unsigned u; float f; } v; v.u = u;
    return v.f;
}

// ---- K0: fused parallel prep: xcast | wcast(transpose) | hsum zero | edge count ----
__global__ __launch_bounds__(256) void prep_kernel(const float* __restrict__ x,
                                                   const float* __restrict__ W,
                                                   const int* __restrict__ ei,
                                                   unsigned short* __restrict__ xbf,
                                                   unsigned short* __restrict__ wt,
                                                   float* __restrict__ hsum,
                                                   int* __restrict__ cnt) {
    const int bid = blockIdx.x, tid = threadIdx.x;
    if (bid < 1250) {
        int t = bid * 256 + tid;  // exactly 320000
        float4 v = ((const float4*)x)[t];
        ushort4 o;
        o.x = f2bf(v.x); o.y = f2bf(v.y); o.z = f2bf(v.z); o.w = f2bf(v.w);
        ((ushort4*)xbf)[t] = o;
    } else if (bid < 1650) {
        int t = (bid - 1250) * 256 + tid;  // exactly 102400
        int n = t >> 7, k = t & 127;
        wt[t] = f2bf(W[k * NHID + n]);
    } else if (bid < 1807) {
        int t = (bid - 1650) * 256 + tid;
        if (t < 40000) ((float4*)hsum)[t] = make_float4(0.f, 0.f, 0.f, 0.f);
    } else {
        int e = (bid - 1807) * 256 + tid;
        if (e < N_EDGES) atomicAdd(&cnt[ei[N_EDGES + e]], 1);
    }
}

// ---- K1: MFMA bf16 GEMM, LDS-free, alpha fused (pre-scaled by log2e) ----
__global__ __launch_bounds__(256) void gemm_mfma(const unsigned short* __restrict__ xbf,
                                                 const unsigned short* __restrict__ wt,
                                                 const float* __restrict__ a_src,
                                                 const float* __restrict__ a_dst,
                                                 unsigned short* __restrict__ xpg,
                                                 float* __restrict__ astp,
                                                 float* __restrict__ adtp) {
    const int tid = threadIdx.x;
    const int wave = tid >> 6, lane = tid & 63;
    const int q = lane >> 4, r = lane & 15;
    const int m0 = blockIdx.y * 128 + wave * 32;
    const int h0 = blockIdx.x * 5;
    ffrag zf = {0.f, 0.f, 0.f, 0.f};
    ffrag acc[2][5];
#pragma unroll
    for (int mt = 0; mt < 2; mt++)
#pragma unroll
        for (int nt = 0; nt < 5; nt++) acc[mt][nt] = zf;

#pragma unroll
    for (int kc = 0; kc < IN_DIM; kc += 32) {
        bfrag a[2], b[5];
#pragma unroll
        for (int mt = 0; mt < 2; mt++)
            a[mt] = *(const bfrag*)(xbf + (m0 + mt * 16 + r) * IN_DIM + kc + q * 8);
#pragma unroll
        for (int nt = 0; nt < 5; nt++)
            b[nt] = *(const bfrag*)(wt + ((h0 + nt) * 16 + r) * IN_DIM + kc + q * 8);
#pragma unroll
        for (int mt = 0; mt < 2; mt++)
#pragma unroll
            for (int nt = 0; nt < 5; nt++)
                acc[mt][nt] = __builtin_amdgcn_mfma_f32_16x16x32_bf16(a[mt], b[nt],
                                                                      acc[mt][nt], 0, 0, 0);
    }
#pragma unroll
    for (int nt = 0; nt < 5; nt++) {
        const int h = h0 + nt;
        const int g = (8 * h + 7) / 50;
        const int hl = h - hstart_of(g);
        const float asw = a_src[h * HID + r] * LOG2E;
        const float adw = a_dst[h * HID + r] * LOG2E;
        unsigned short* xg = xpg + (size_t)g * (N_NODES * 128);
        float* ag = astp + g * (N_NODES * 8);
        float* dg = adtp + g * (N_NODES * 8);
#pragma unroll
        for (int mt = 0; mt < 2; mt++) {
            ffrag d = acc[mt][nt];  // rows m = m0+mt*16+q*4+i, col r
            float s[4], w[4];
#pragma unroll
            for (int i = 0; i < 4; i++) { s[i] = d[i] * asw; w[i] = d[i] * adw; }
#pragma unroll
            for (int off = 1; off < 16; off <<= 1) {
#pragma unroll
                for (int i = 0; i < 4; i++) {
                    s[i] += __shfl_xor(s[i], off);
                    w[i] += __shfl_xor(w[i], off);
                }
            }
#pragma unroll
            for (int i = 0; i < 4; i++) {
                const int node = m0 + mt * 16 + q * 4 + i;
                if (node < N_NODES) {
                    xg[node * 128 + hl * 16 + r] = f2bf(d[i]);
                    if (r == 0) {
                        ag[(node << 3) + hl] = s[i];
                        dg[(node << 3) + hl] = w[i];
                    }
                }
            }
        }
    }
}

// ---- K2: scan (1 block, shfl-based): cnt -> offs/curs, degree hist -> dcur ----
__global__ __launch_bounds__(1024) void scan_kernel(const int* __restrict__ cnt,
                                                    int* __restrict__ offs,
                                                    int* __restrict__ curs,
                                                    int* __restrict__ dcur) {
    __shared__ int wsum[16];
    __shared__ int dh[64];
    const int t = threadIdx.x;
    const int wid = t >> 6, lane = t & 63;
    if (t < 64) dh[t] = 0;
    __syncthreads();
    const int base = t * 10;
    int local[10];
    int s = 0;
#pragma unroll
    for (int i = 0; i < 10; i++) {
        int idx = base + i;
        int v = (idx < N_NODES) ? cnt[idx] : 0;
        if (idx < N_NODES) { int bb = v < 63 ? v : 63; atomicAdd(&dh[63 - bb], 1); }
        local[i] = s;
        s += v;
    }
    int incl = s;  // wave-level inclusive scan via shfl_up
#pragma unroll
    for (int off = 1; off < 64; off <<= 1) {
        int u = __shfl_up(incl, off);
        if (lane >= off) incl += u;
    }
    if (lane == 63) wsum[wid] = incl;
    __syncthreads();
    if (wid == 0 && lane < 16) {
        int v = wsum[lane];
        int i2 = v;
#pragma unroll
        for (int off = 1; off < 16; off <<= 1) {
            int u = __shfl_up(i2, off);
            if (lane >= off) i2 += u;
        }
        wsum[lane] = i2 - v;  // exclusive wave offset
    }
    __syncthreads();
    const int texcl = (incl - s) + wsum[wid];
#pragma unroll
    for (int i = 0; i < 10; i++) {
        int idx = base + i;
        if (idx < N_NODES) {
            int o = texcl + local[i];
            offs[idx] = o;
            curs[idx] = o;
        }
    }
    if (t == 1023) offs[N_NODES] = texcl + s;  // == N_EDGES
    if (wid == 0) {
        int v = dh[lane];
        int i3 = v;
#pragma unroll
        for (int off = 1; off < 64; off <<= 1) {
            int u = __shfl_up(i3, off);
            if (lane >= off) i3 += u;
        }
        dcur[lane] = i3 - v;  // exclusive (descending-degree bins)
    }
}

// ---- K3: fused parallel scatter: edge scatter | degree-sort scatter ----
__global__ __launch_bounds__(256) void scatter_kernel(const int* __restrict__ ei,
                                                      int* __restrict__ curs,
                                                      int* __restrict__ ssrc,
                                                      const int* __restrict__ cnt,
                                                      int* __restrict__ dcur,
                                                      int* __restrict__ perm) {
    const int bid = blockIdx.x;
    if (bid < 625) {
        int e = bid * 256 + threadIdx.x;
        if (e < N_EDGES) {
            int d = ei[N_EDGES + e];
            int pos = atomicAdd(&curs[d], 1);
            ssrc[pos] = ei[e];
        }
    } else {
        int n = (bid - 625) * 256 + threadIdx.x;
        if (n < N_NODES) {
            int d = cnt[n];
            d = d < 63 ? d : 63;
            int pos = atomicAdd(&dcur[63 - d], 1);  // descending degree
            perm[pos] = n;
        }
    }
}

// ---- K4: chunk-deduped aggregation ----
// grid 20000 = 8 grps x 2500 (blockIdx&7 -> XCD; slice L2-resident). Wave owns
// dst = perm[db*4+wave]. Edges processed in chunks of 8:
//   compute phase: lane (esub=lane&7, head=lane>>3) computes w once per
//     (edge, head) -- 8x dedup of exp vs per-channel-lane recompute;
//   accum phase: lane (hl=lane>>3, c2) pulls w via ds_bpermute
//     (__shfl variable lane (lane&56)|j) and fmas its 2 channels.
// Tail edges clamped to eend-1 with w=0 (no divergence, no OOB).
__global__ __launch_bounds__(256) void agg_kernel(const unsigned short* __restrict__ xpg,
                                                  const float* __restrict__ astp,
                                                  const float* __restrict__ adtp,
                                                  const int* __restrict__ offs,
                                                  const int* __restrict__ ssrc,
                                                  const int* __restrict__ perm,
                                                  float* __restrict__ hsum) {
    const int t = threadIdx.x;
    const int wave = t >> 6, lane = t & 63;
    const int g = blockIdx.x & 7;
    const int db = blockIdx.x >> 3;  // 0..2499
    const int cg = hstart_of(g + 1) - hstart_of(g);  // 6 or 7
    const int hl = lane >> 3;
    const int esub = lane & 7;
    const int co = (hl << 4) + esub * 2;  // element offset in 128-wide row
    const int wbase = lane & 56;          // shfl source base = head's lane block
    const int dst = __builtin_amdgcn_readfirstlane(perm[db * 4 + wave]);
    const int start = __builtin_amdgcn_readfirstlane(offs[dst]);
    const int eend = __builtin_amdgcn_readfirstlane(offs[dst + 1]);
    const float* ag = astp + g * (N_NODES * 8);
    const unsigned short* xg = xpg + (size_t)g * (N_NODES * 128);
    const float adv = adtp[g * (N_NODES * 8) + (dst << 3) + hl];
    // self loop (exp once per (dst, head); same value across a head's 8 lanes)
    float lS = ag[(dst << 3) + hl] + adv;
    lS = fmaxf(lS, 0.2f * lS);
    const float wS = exp2f(lS);
    const unsigned pS = *(const unsigned*)(xg + (dst << 7) + co);
    float den = wS;
    float acc0 = wS * bits2f(pS << 16);
    float acc1 = wS * bits2f(pS & 0xffff0000u);
    const int elast = eend - 1;
    for (int base = start; base < eend; base += 8) {
        // compute phase: w for (edge base+esub, head hl), computed ONCE
        const int eidx = base + esub;
        const int ecl = (eidx < elast) ? eidx : elast;
        const int sE = ssrc[ecl];
        float l = ag[(sE << 3) + hl] + adv;
        l = fmaxf(l, 0.2f * l);
        const float w = (eidx < eend) ? exp2f(l) : 0.f;
        // accum phase: 8 edges, weights via bpermute, px coalesced from L2
#pragma unroll
        for (int j = 0; j < 8; j++) {
            const int ej = (base + j < elast) ? (base + j) : elast;
            const int sj = __builtin_amdgcn_readfirstlane(ssrc[ej]);
            const float wj = __shfl(w, wbase + j);
            const unsigned p = *(const unsigned*)(xg + (sj << 7) + co);
            den += wj;
            acc0 = fmaf(wj, bits2f(p << 16), acc0);
            acc1 = fmaf(wj, bits2f(p & 0xffff0000u), acc1);
        }
    }
    const float inv = (hl < cg) ? (1.f / den) : 0.f;  // den>0: self loop
    float v0 = acc0 * inv, v1 = acc1 * inv;
    v0 += __shfl_xor(v0, 8);  v1 += __shfl_xor(v1, 8);
    v0 += __shfl_xor(v0, 16); v1 += __shfl_xor(v1, 16);
    v0 += __shfl_xor(v0, 32); v1 += __shfl_xor(v1, 32);
    if (lane < 8) {
        atomicAdd(&hsum[(dst << 4) + 2 * lane + 0], v0);
        atomicAdd(&hsum[(dst << 4) + 2 * lane + 1], v1);
    }
}

// ---- K5: per-graph mean pool (+ head mean + bias) + FC. One block per graph. ----
__global__ __launch_bounds__(256) void pool_kernel(const float* __restrict__ hsum,
                                                   const int* __restrict__ batch,
                                                   const float* __restrict__ bias,
                                                   const float* __restrict__ fc_w,
                                                   const float* __restrict__ fc_b,
                                                   float* __restrict__ out) {
    const int g = blockIdx.x;
    const int t = threadIdx.x;
    int a = 0, b = N_NODES;
    while (a < b) { int m = (a + b) >> 1; if (batch[m] < g) a = m + 1; else b = m; }
    const int lo = a;
    b = N_NODES;
    while (a < b) { int m = (a + b) >> 1; if (batch[m] < g + 1) a = m + 1; else b = m; }
    const int hi = a;
    const int cntn = hi - lo;
    float acc[16];
#pragma unroll
    for (int c = 0; c < 16; c++) acc[c] = 0.f;
    for (int n = lo + t; n < hi; n += 256) {
        const float4* r = (const float4*)(hsum + (n << 4));
        float4 v0 = r[0], v1 = r[1], v2 = r[2], v3 = r[3];
        acc[0] += v0.x; acc[1] += v0.y; acc[2] += v0.z; acc[3] += v0.w;
        acc[4] += v1.x; acc[5] += v1.y; acc[6] += v1.z; acc[7] += v1.w;
        acc[8] += v2.x; acc[9] += v2.y; acc[10] += v2.z; acc[11] += v2.w;
        acc[12] += v3.x; acc[13] += v3.y; acc[14] += v3.z; acc[15] += v3.w;
    }
    __shared__ float red[256][17];
#pragma unroll
    for (int c = 0; c < 16; c++) red[t][c] = acc[c];
    __syncthreads();
    for (int s = 128; s > 0; s >>= 1) {
        if (t < s)
#pragma unroll
            for (int c = 0; c < 16; c++) red[t][c] += red[t + s][c];
        __syncthreads();
    }
    __shared__ float pooled[16];
    if (t < 16) {
        float v = 0.f;
        if (cntn > 0) v = red[0][t] / ((float)cntn * (float)HEADS) + bias[t];
        pooled[t] = v;
    }
    __syncthreads();
    if (t < OUT_DIM) {
        float s = fc_b[t];
#pragma unroll
        for (int c = 0; c < HID; c++) s += pooled[c] * fc_w[c * OUT_DIM + t];
        out[g * OUT_DIM + t] = s;
    }
}

// ---- workspace layout (bytes) ----
#define XPG_OFF 0              /* 8*10000*8*16*2 = 20,480,000 */
#define ASTP_OFF 20480000      /* 8*10000*8*4    =  2,560,000 */
#define ADTP_OFF 23040000      /* 8*10000*8*4    =  2,560,000 */
#define XBF_OFF 25600000       /* 10000*128*2    =  2,560,000 (wt follows: OOB-read safe) */
#define WT_OFF 28160000        /* 800*128*2      =    204,800 */
#define SSRC_OFF 28364800      /* 160000*4       =    640,000 */
#define OFFS_OFF 29004800      /* 10001*4        =     40,064 padded */
#define CURS_OFF 29044864      /* 10000*4        =     40,000 */
#define PERM_OFF 29084864      /* 10000*4        =     40,000 */
#define HSUM_OFF 29124864      /* 10000*16*4     =    640,000 (zeroed in prep) */
#define CNT_OFF 29764864       /* 10000*4        =     40,000 (zeroed by memset) */
#define DCUR_OFF 29804864      /* 64*4           =        256 */

extern "C" void kernel_launch(void* const* d_in, const int* in_sizes, int n_in,
                              void* d_out, int out_size, void* d_ws, size_t ws_size,
                              hipStream_t stream) {
    const float* x = (const float*)d_in[0];
    const int* ei = (const int*)d_in[1];
    const int* batch = (const int*)d_in[2];
    const float* W = (const float*)d_in[4];
    const float* a_src = (const float*)d_in[5];
    const float* a_dst = (const float*)d_in[6];
    const float* bias = (const float*)d_in[7];
    const float* fc_w = (const float*)d_in[8];
    const float* fc_b = (const float*)d_in[9];
    float* out = (float*)d_out;

    char* ws = (char*)d_ws;
    unsigned short* xpg = (unsigned short*)(ws + XPG_OFF);
    float* astp = (float*)(ws + ASTP_OFF);
    float* adtp = (float*)(ws + ADTP_OFF);
    unsigned short* xbf = (unsigned short*)(ws + XBF_OFF);
    unsigned short* wt = (unsigned short*)(ws + WT_OFF);
    int* ssrc = (int*)(ws + SSRC_OFF);
    int* offs = (int*)(ws + OFFS_OFF);
    int* curs = (int*)(ws + CURS_OFF);
    int* perm = (int*)(ws + PERM_OFF);
    float* hsum = (float*)(ws + HSUM_OFF);
    int* cntc = (int*)(ws + CNT_OFF);
    int* dcur = (int*)(ws + DCUR_OFF);

    hipMemsetAsync(ws + CNT_OFF, 0, 40000, stream);
    prep_kernel<<<2432, 256, 0, stream>>>(x, W, ei, xbf, wt, hsum, cntc);
    gemm_mfma<<<dim3(10, (N_NODES + 127) / 128), 256, 0, stream>>>(
        xbf, wt, a_src, a_dst, xpg, astp, adtp);
    scan_kernel<<<1, 1024, 0, stream>>>(cntc, offs, curs, dcur);
    scatter_kernel<<<665, 256, 0, stream>>>(ei, curs, ssrc, cntc, dcur, perm);
    agg_kernel<<<8 * (N_NODES / 4), 256, 0, stream>>>(xpg, astp, adtp, offs, ssrc, perm, hsum);
    pool_kernel<<<N_GRAPHS, 256, 0, stream>>>(hsum, batch, bias, fc_w, fc_b, out);
}